// Round 2
// baseline (111.798 us; speedup 1.0000x reference)
//
#include <hip/hip_runtime.h>
#include <hip/hip_bf16.h>

#define IN_DIM 512
#define OUT_DIM 512
#define BATCH 4096
#define NC 9                  // 8 active spline basis slots + 1 silu slot
#define KDIM (IN_DIM * NC)    // 4608
#define NCTRL 17
#define TILE 128
#define BKT 64
#define SPLITK 8
#define KSLICE (KDIM / SPLITK)       // 576
#define KSTEPS (KSLICE / BKT)        // 9

typedef unsigned short ushort_t;
typedef __attribute__((ext_vector_type(8))) short short8;
typedef __attribute__((ext_vector_type(4))) float f32x4;

__device__ inline ushort_t to_bf16(float f) {
    union { float f; unsigned int i; } v; v.f = f;
    unsigned int r = v.i + 0x7FFF + ((v.i >> 16) & 1);   // round-to-nearest-even
    return (ushort_t)(r >> 16);
}

__device__ inline void gld16(const ushort_t* g, ushort_t* l) {
    __builtin_amdgcn_global_load_lds(
        (const __attribute__((address_space(1))) void*)g,
        (__attribute__((address_space(3))) void*)l, 16, 0, 0);
}

// Pre-swizzled storage: element (row R, col k) lives at col k ^ ((R&7)<<3).
// XOR touches element bits 3-5 (= byte bits 4-6), i.e. stays inside each
// 128-byte segment, so global_load_lds staging of 64-col tiles is unaffected
// and ds_read applies the same XOR -> 2-way (free) bank aliasing instead of 16.

// Build A' bf16 [OUT_DIM][KDIM]: A'[o][i*9+c] = w_s[i,o]*ctrl[i,o,c] (c<8), w_b[i,o] (c==8)
__global__ void prep_A(const float* __restrict__ w_b, const float* __restrict__ w_s,
                       const float* __restrict__ ctrl, ushort_t* __restrict__ A) {
    int tid = blockIdx.x * 256 + threadIdx.x;
    int i = tid & (IN_DIM - 1);
    int o = tid >> 9;
    float ws = w_s[i * OUT_DIM + o];
    float wb = w_b[i * OUT_DIM + o];
    const float* cp = ctrl + (size_t)(i * OUT_DIM + o) * NCTRL;
    size_t rbase = (size_t)o * KDIM;
    int swz = (o & 7) << 3;
    int k0 = i * NC;
#pragma unroll
    for (int c = 0; c < 8; c++) A[rbase + ((k0 + c) ^ swz)] = to_bf16(ws * cp[c]);
    A[rbase + ((k0 + 8) ^ swz)] = to_bf16(wb);
}

// Build B' bf16 [BATCH][KDIM]: B'[b][i*9+c] = basis_c(t) (c<8), silu(t) (c==8)
__global__ void prep_B(const float* __restrict__ x, const float* __restrict__ g,
                       const float* __restrict__ bound_p, ushort_t* __restrict__ Bt) {
    int tid = blockIdx.x * 256 + threadIdx.x;
    int i = tid & (IN_DIM - 1);
    int b = tid >> 9;
    float bound = bound_p[0];
    float t = x[(size_t)b * IN_DIM + i];
    t = fminf(fmaxf(t, -bound), bound);
    float u = (t + 8.0f) * 0.625f;       // knot spacing 1.6 -> 1/1.6 = 0.625 exact
    int j = (int)u;                       // interval: g[j] <= t < g[j+1], j in [2,7]
    j = min(max(j, 2), 7);
    // knots g[j-2 .. j+3]
    float gj[6];
#pragma unroll
    for (int r = 0; r < 6; r++) gj[r] = g[j - 2 + r];
    // de Boor; uniform knots -> denominators are p*1.6 (constants)
    const float invph[4] = {0.f, 0.625f, 0.3125f, 0.2083333333f};
    float Nv[4]; Nv[0] = 1.0f;
    float lv[4], rv[4];
#pragma unroll
    for (int p = 1; p <= 3; p++) {
        lv[p] = t - gj[3 - p];           // t - g[j+1-p]
        rv[p] = gj[2 + p] - t;           // g[j+p] - t
        float saved = 0.0f;
#pragma unroll
        for (int r = 0; r < p; r++) {
            float temp = Nv[r] * invph[p];
            Nv[r] = saved + rv[r + 1] * temp;
            saved = lv[p - r] * temp;
        }
        Nv[p] = saved;
    }
    int c0 = j - 3;                       // may be -1 at j==2: drop Nv[0] (B_{-1} doesn't exist)
    size_t rbase = (size_t)b * KDIM;
    int swz = (b & 7) << 3;
    int k0 = i * NC;
#pragma unroll
    for (int c = 0; c < 8; c++) {
        float v = 0.0f;
        v = (c == c0    ) ? Nv[0] : v;
        v = (c == c0 + 1) ? Nv[1] : v;
        v = (c == c0 + 2) ? Nv[2] : v;
        v = (c == c0 + 3) ? Nv[3] : v;
        Bt[rbase + ((k0 + c) ^ swz)] = to_bf16(v);
    }
    float sg = 1.0f / (1.0f + __expf(-t));
    Bt[rbase + ((k0 + 8) ^ swz)] = to_bf16(t * sg);
}

// C[b][o] = sum_k B'[b][k] * A'[o][k].
// 128x128 tile, BK=64, 4 waves (2x2 of 64x64), 16x16x32 bf16 MFMA,
// split-K=8 via fp32 atomicAdd into zeroed d_out (grid 1024 = 4 blocks/CU).
__global__ __launch_bounds__(256, 4) void gemm_kan(const ushort_t* __restrict__ A,
                                                    const ushort_t* __restrict__ Bt,
                                                    float* __restrict__ out) {
    __shared__ ushort_t Xs[TILE * BKT];   // batch-side tile [128][64]
    __shared__ ushort_t Ys[TILE * BKT];   // out-side tile  [128][64]
    int tid = threadIdx.x;
    int lane = tid & 63;
    int w = tid >> 6;
    int bid = blockIdx.x;
    // bid = kz*128 + ot*32 + bt : all blocks sharing a B-panel (same bt) have
    // bid == bt (mod 8) -> same XCD under round-robin -> B fetched once/XCD.
    int kz = bid >> 7;
    int ot = (bid >> 5) & 3;      // out tile   (512/128)
    int bt = bid & 31;            // batch tile (4096/128)
    int brow0 = bt * TILE;
    int ocol0 = ot * TILE;
    int k0 = kz * KSLICE;

    int wr = w >> 1, wc = w & 1;  // wave sub-tile (64x64) within 128x128

    f32x4 acc[4][4];
#pragma unroll
    for (int m = 0; m < 4; m++)
#pragma unroll
        for (int n = 0; n < 4; n++) acc[m][n] = (f32x4){0.f, 0.f, 0.f, 0.f};

    int lr = lane >> 3;           // staging: lane's row within 8-row group
    int lcb = (lane & 7) * 8;     // staging: lane's bf16 col (16B granules)

    for (int ks = 0; ks < KSTEPS; ks++) {
        int kcur = k0 + ks * BKT;
#pragma unroll
        for (int it = 0; it < 4; it++) {
            int row = it * 32 + w * 8;    // wave-uniform LDS dest
            gld16(Bt + (size_t)(brow0 + row + lr) * KDIM + kcur + lcb, &Xs[row * BKT]);
            gld16(A  + (size_t)(ocol0 + row + lr) * KDIM + kcur + lcb, &Ys[row * BKT]);
        }
        __syncthreads();
#pragma unroll
        for (int kk = 0; kk < 2; kk++) {
            short8 xf[4], yf[4];
            int kof = kk * 32 + (lane >> 4) * 8;
            int swz = (lane & 7) << 3;    // rows below have row&7 == lane&7
            int kofs = kof ^ swz;
#pragma unroll
            for (int m = 0; m < 4; m++)
                xf[m] = *(const short8*)&Xs[(wr * 64 + m * 16 + (lane & 15)) * BKT + kofs];
#pragma unroll
            for (int n = 0; n < 4; n++)
                yf[n] = *(const short8*)&Ys[(wc * 64 + n * 16 + (lane & 15)) * BKT + kofs];
#pragma unroll
            for (int m = 0; m < 4; m++)
#pragma unroll
                for (int n = 0; n < 4; n++)
                    acc[m][n] = __builtin_amdgcn_mfma_f32_16x16x32_bf16(xf[m], yf[n], acc[m][n], 0, 0, 0);
        }
        __syncthreads();
    }
    // epilogue: C row=b=(lane>>4)*4+reg (+16m+64wr), col=o=lane&15 (+16n+64wc)
    int rgrp = lane >> 4;
    int cidx = lane & 15;
#pragma unroll
    for (int m = 0; m < 4; m++) {
#pragma unroll
        for (int n = 0; n < 4; n++) {
            int o_idx = ocol0 + wc * 64 + n * 16 + cidx;
#pragma unroll
            for (int r = 0; r < 4; r++) {
                int b_idx = brow0 + wr * 64 + m * 16 + rgrp * 4 + r;
                atomicAdd(out + (size_t)b_idx * OUT_DIM + o_idx, acc[m][n][r]);
            }
        }
    }
}

extern "C" void kernel_launch(void* const* d_in, const int* in_sizes, int n_in,
                              void* d_out, int out_size, void* d_ws, size_t ws_size,
                              hipStream_t stream) {
    const float* x     = (const float*)d_in[0];
    const float* w_b   = (const float*)d_in[1];
    const float* w_s   = (const float*)d_in[2];
    const float* ctrl  = (const float*)d_in[3];
    const float* g     = (const float*)d_in[4];
    const float* bound = (const float*)d_in[5];
    float* out = (float*)d_out;

    ushort_t* Abuf = (ushort_t*)d_ws;                               // 512*4608*2 = 4.72 MB
    ushort_t* Bbuf = (ushort_t*)((char*)d_ws + (size_t)(8u << 20)); // at 8 MB; 4096*4608*2 = 37.75 MB

    hipMemsetAsync(d_out, 0, (size_t)BATCH * OUT_DIM * sizeof(float), stream);
    prep_A<<<IN_DIM * OUT_DIM / 256, 256, 0, stream>>>(w_b, w_s, ctrl, Abuf);
    prep_B<<<BATCH * IN_DIM / 256, 256, 0, stream>>>(x, g, bound, Bbuf);
    gemm_kan<<<SPLITK * 128, 256, 0, stream>>>(Abuf, Bbuf, out);
}

// Round 3
// 52.439 us; speedup vs baseline: 2.1320x; 2.1320x over previous
//
#include <hip/hip_runtime.h>
#include <hip/hip_bf16.h>

#define IN_DIM 512
#define OUT_DIM 512
#define BATCH 4096
#define NC 9                  // 8 active spline basis slots + 1 silu slot
#define KDIM (IN_DIM * NC)    // 4608
#define NCTRL 17
#define TM 128                // batch rows per block
#define TN 64                 // out cols per block
#define BK 64
#define NT (KDIM / BK)        // 72 K-steps
// ring buffer: 4 x (TM*BK + TN*BK) bf16 = 4 x 24576 B = 96 KiB LDS
#define BUF_ELEMS 12288
#define BUF_BYTES 24576

typedef unsigned short ushort_t;
typedef __attribute__((ext_vector_type(8))) short short8;
typedef __attribute__((ext_vector_type(4))) float f32x4;

__device__ inline ushort_t to_bf16(float f) {
    union { float f; unsigned int i; } v; v.f = f;
    unsigned int r = v.i + 0x7FFF + ((v.i >> 16) & 1);   // round-to-nearest-even
    return (ushort_t)(r >> 16);
}

__device__ inline void gld16(const ushort_t* g, void* l) {
    __builtin_amdgcn_global_load_lds(
        (const __attribute__((address_space(1))) void*)g,
        (__attribute__((address_space(3))) void*)l, 16, 0, 0);
}

// Pre-swizzled storage: element (row R, col k) lives at col k ^ ((R&7)<<3).
// XOR touches element bits 3-5 only -> permutes 16B chunks inside each 128B
// segment, so linear global_load_lds staging of 64-col tiles is unaffected;
// ds_read applies the same XOR -> 2-way (free) bank aliasing.

// Build A' bf16 [OUT_DIM][KDIM]: A'[o][i*9+c] = w_s[i,o]*ctrl[i,o,c] (c<8), w_b[i,o] (c==8)
__global__ void prep_A(const float* __restrict__ w_b, const float* __restrict__ w_s,
                       const float* __restrict__ ctrl, ushort_t* __restrict__ A) {
    int tid = blockIdx.x * 256 + threadIdx.x;
    int i = tid & (IN_DIM - 1);
    int o = tid >> 9;
    float ws = w_s[i * OUT_DIM + o];
    float wb = w_b[i * OUT_DIM + o];
    const float* cp = ctrl + (size_t)(i * OUT_DIM + o) * NCTRL;
    size_t rbase = (size_t)o * KDIM;
    int swz = (o & 7) << 3;
    int k0 = i * NC;
#pragma unroll
    for (int c = 0; c < 8; c++) A[rbase + ((k0 + c) ^ swz)] = to_bf16(ws * cp[c]);
    A[rbase + ((k0 + 8) ^ swz)] = to_bf16(wb);
}

// Build B' bf16 [BATCH][KDIM]: B'[b][i*9+c] = basis_c(t) (c<8), silu(t) (c==8)
// One block per batch row: de Boor -> swizzled LDS row -> coalesced 16B stores.
__global__ __launch_bounds__(512) void prep_B(const float* __restrict__ x,
                                              const float* __restrict__ g,
                                              const float* __restrict__ bound_p,
                                              ushort_t* __restrict__ Bt) {
    __shared__ ushort_t rowbuf[KDIM];
    int b = blockIdx.x;
    int i = threadIdx.x;
    float bound = bound_p[0];
    float t = x[(size_t)b * IN_DIM + i];
    t = fminf(fmaxf(t, -bound), bound);
    float u = (t + 8.0f) * 0.625f;       // knot spacing 1.6 -> 1/1.6 = 0.625 exact
    int j = (int)u;                       // interval: g[j] <= t < g[j+1], j in [2,7]
    j = min(max(j, 2), 7);
    float gj[6];
#pragma unroll
    for (int r = 0; r < 6; r++) gj[r] = g[j - 2 + r];
    // de Boor; uniform knots -> denominators are p*1.6 (constants)
    const float invph[4] = {0.f, 0.625f, 0.3125f, 0.2083333333f};
    float Nv[4]; Nv[0] = 1.0f;
    float lv[4], rv[4];
#pragma unroll
    for (int p = 1; p <= 3; p++) {
        lv[p] = t - gj[3 - p];
        rv[p] = gj[2 + p] - t;
        float saved = 0.0f;
#pragma unroll
        for (int r = 0; r < p; r++) {
            float temp = Nv[r] * invph[p];
            Nv[r] = saved + rv[r + 1] * temp;
            saved = lv[p - r] * temp;
        }
        Nv[p] = saved;
    }
    int c0 = j - 3;                       // c0 == -1 at j==2: Nv[0] (B_{-1}) is dropped
    int swz = (b & 7) << 3;
    int k0 = i * NC;
#pragma unroll
    for (int c = 0; c < 8; c++) {
        float v = 0.0f;
        v = (c == c0    ) ? Nv[0] : v;
        v = (c == c0 + 1) ? Nv[1] : v;
        v = (c == c0 + 2) ? Nv[2] : v;
        v = (c == c0 + 3) ? Nv[3] : v;
        rowbuf[(k0 + c) ^ swz] = to_bf16(v);
    }
    float sg = 1.0f / (1.0f + __expf(-t));
    rowbuf[(k0 + 8) ^ swz] = to_bf16(t * sg);
    __syncthreads();
    const uint4* s = (const uint4*)rowbuf;               // 576 x 16B chunks
    uint4* d = (uint4*)(Bt + (size_t)b * KDIM);
    d[i] = s[i];
    if (i < 64) d[512 + i] = s[512 + i];
}

// C[b][o] = sum_k B'[b][k] * A'[o][k].  Tile TM=128 x TN=64, grid 32x8=256,
// 8 waves (4M x 2N, each 32x32), ring-4 LDS, counted vmcnt (never 0 in loop),
// one raw s_barrier per K-step. Direct fp32 stores, no split-K, no atomics.
__global__ __launch_bounds__(512) void gemm_kan(const ushort_t* __restrict__ A,
                                                const ushort_t* __restrict__ Bt,
                                                float* __restrict__ out) {
    __shared__ ushort_t ring[4 * BUF_ELEMS];   // 96 KiB
    int tid = threadIdx.x;
    int lane = tid & 63;
    int w = tid >> 6;             // 0..7
    int bid = blockIdx.x;
    // bid = ot*32 + bt: the 8 ot-blocks of one bt (sharing the B'-panel) have
    // equal bid mod 8 -> same XCD under round-robin -> panel L2-shared.
    int ot = bid >> 5;            // 0..7
    int bt = bid & 31;            // 0..31
    int brow0 = bt * TM;
    int ocol0 = ot * TN;

    int wr = w >> 1;              // 0..3 : M sub-tile (32 rows)
    int wc = w & 1;               // 0..1 : N sub-tile (32 cols)

    f32x4 acc[2][2];
#pragma unroll
    for (int m = 0; m < 2; m++)
#pragma unroll
        for (int n = 0; n < 2; n++) acc[m][n] = (f32x4){0.f, 0.f, 0.f, 0.f};

    // staging: 24 x 1KB issues/step (16 for Xs=B'-tile, 8 for Ys=A'-tile);
    // wave w owns issues f = 3w..3w+2. LDS dst is linear: buf + f*1024.
    int lr = lane >> 3;           // row within 8-row group
    int lcb = (lane & 7) * 8;     // 16B chunk within 64-col row
    const ushort_t* src[3];
    int ldsoff[3];
#pragma unroll
    for (int i = 0; i < 3; i++) {
        int f = w * 3 + i;
        const ushort_t* basep = (f < 16)
            ? Bt + (size_t)(brow0 + f * 8 + lr) * KDIM
            : A  + (size_t)(ocol0 + (f - 16) * 8 + lr) * KDIM;
        src[i] = basep + lcb;
        ldsoff[i] = f * 1024;
    }
    char* ringb = (char*)ring;

#define STAGE(T) do { int bb_ = ((T) & 3) * BUF_BYTES;                         \
    _Pragma("unroll") for (int i_ = 0; i_ < 3; i_++)                           \
        gld16(src[i_] + (size_t)(T) * BK, ringb + bb_ + ldsoff[i_]); } while (0)

#define COMPUTE(T) do {                                                        \
    const ushort_t* Xs_ = ring + ((T) & 3) * BUF_ELEMS;                        \
    const ushort_t* Ys_ = Xs_ + TM * BK;                                       \
    int xrow_ = wr * 32 + (lane & 15);                                         \
    int yrow_ = wc * 32 + (lane & 15);                                         \
    int swz_ = (lane & 7) << 3;                                                \
    _Pragma("unroll") for (int kk_ = 0; kk_ < 2; kk_++) {                      \
        int kofs_ = (kk_ * 32 + ((lane >> 4) << 3)) ^ swz_;                    \
        short8 xf0 = *(const short8*)&Xs_[(xrow_     ) * BK + kofs_];          \
        short8 xf1 = *(const short8*)&Xs_[(xrow_ + 16) * BK + kofs_];          \
        short8 yf0 = *(const short8*)&Ys_[(yrow_     ) * BK + kofs_];          \
        short8 yf1 = *(const short8*)&Ys_[(yrow_ + 16) * BK + kofs_];          \
        acc[0][0] = __builtin_amdgcn_mfma_f32_16x16x32_bf16(xf0, yf0, acc[0][0], 0, 0, 0); \
        acc[0][1] = __builtin_amdgcn_mfma_f32_16x16x32_bf16(xf0, yf1, acc[0][1], 0, 0, 0); \
        acc[1][0] = __builtin_amdgcn_mfma_f32_16x16x32_bf16(xf1, yf0, acc[1][0], 0, 0, 0); \
        acc[1][1] = __builtin_amdgcn_mfma_f32_16x16x32_bf16(xf1, yf1, acc[1][1], 0, 0, 0); \
    } } while (0)

#define WAITVM(N) asm volatile("s_waitcnt vmcnt(" #N ")" ::: "memory")
#define BARRIER() do { __builtin_amdgcn_sched_barrier(0);                      \
    __builtin_amdgcn_s_barrier();                                             \
    __builtin_amdgcn_sched_barrier(0);                                        \
    asm volatile("" ::: "memory"); } while (0)

    // prologue: 3 tiles in flight (9 gld16/wave outstanding)
    STAGE(0); STAGE(1); STAGE(2);
    // steady state: wait tile t (leave 6 in flight), barrier, stage t+3, compute t
    for (int t = 0; t < NT - 3; ++t) {
        WAITVM(6);
        BARRIER();
        STAGE(t + 3);
        COMPUTE(t);
    }
    WAITVM(6); BARRIER(); COMPUTE(NT - 3);
    WAITVM(3); BARRIER(); COMPUTE(NT - 2);
    WAITVM(0); BARRIER(); COMPUTE(NT - 1);

    // epilogue: C/D layout col=lane&15, row=(lane>>4)*4+reg (m89)
    int rgrp = (lane >> 4) * 4;
    int cidx = lane & 15;
#pragma unroll
    for (int m = 0; m < 2; m++) {
#pragma unroll
        for (int n = 0; n < 2; n++) {
            int o_idx = ocol0 + wc * 32 + n * 16 + cidx;
            int b_base = brow0 + wr * 32 + m * 16 + rgrp;
#pragma unroll
            for (int r = 0; r < 4; r++)
                out[(size_t)(b_base + r) * OUT_DIM + o_idx] = acc[m][n][r];
        }
    }
#undef STAGE
#undef COMPUTE
#undef WAITVM
#undef BARRIER
}

extern "C" void kernel_launch(void* const* d_in, const int* in_sizes, int n_in,
                              void* d_out, int out_size, void* d_ws, size_t ws_size,
                              hipStream_t stream) {
    const float* x     = (const float*)d_in[0];
    const float* w_b   = (const float*)d_in[1];
    const float* w_s   = (const float*)d_in[2];
    const float* ctrl  = (const float*)d_in[3];
    const float* g     = (const float*)d_in[4];
    const float* bound = (const float*)d_in[5];
    float* out = (float*)d_out;

    ushort_t* Abuf = (ushort_t*)d_ws;                               // 512*4608*2 = 4.72 MB
    ushort_t* Bbuf = (ushort_t*)((char*)d_ws + (size_t)(8u << 20)); // at 8 MB; 4096*4608*2 = 37.75 MB

    prep_A<<<IN_DIM * OUT_DIM / 256, 256, 0, stream>>>(w_b, w_s, ctrl, Abuf);
    prep_B<<<BATCH, 512, 0, stream>>>(x, g, bound, Bbuf);
    gemm_kan<<<(BATCH / TM) * (OUT_DIM / TN), 512, 0, stream>>>(Abuf, Bbuf, out);
}